// Round 1
// baseline (730.052 us; speedup 1.0000x reference)
//
#include <hip/hip_runtime.h>
#include <hip/hip_bf16.h>
#include <math.h>

// dims
#define SS 3
#define BB 2
#define NN 2048
#define KK 16
#define MM 32
#define CC 256
#define BN_TOT 4096
#define SCALE 0.0625f   // 1/sqrt(256)

// ws offsets (in floats)
#define OFF_ACAT   0          // A_cat   [256][768]  A_cat[c][s*256+c'] = sum_d Wq_t[s][c][d]*Wk_t[s][c'][d]
#define OFF_ABCAT  196608     // ab_cat  [768]
#define OFF_VOCAT  197376     // Vo_cat  [768][256]  Vo_cat[s*256+c][e] = sum_d Wv_t[s][c][d]*Wo_t[s][d][e]
#define OFF_VBSUM  393984     // vb_sum  [256]
#define OFF_AC     394240     // A_c     [256][256]
#define OFF_ABC    459776     // ab_c    [256]
#define OFF_VOC    460032     // Vo_c    [256][256]
#define OFF_VBC    525568     // vb_c    [256]
#define OFF_A2     525824     // A2      [768][256] = Vo_cat @ A_c
#define OFF_AB2    722432     // ab2     [256]
#define OFF_QKCAT  722688     // qk_cat  [4096][768]
#define OFF_WKV    3868416    // wkv_cat [4096][768]
#define OFF_QK2    7014144    // qk2     [4096][256]
#define OFF_WS2    8062720    // ws2     [4096][256]
// total 9111296 floats = ~36.4 MB

// ---------------------------------------------------------------------------
// small C-sized matmul helper: 8 output rows x 256 cols per block, 256 thr
// nt=1: OUT[r][c] = sum_d L[r][d] * R[c][d]   (L ld 256, R ld 256)
// nt=0: OUT[r][c] = sum_d L[r][d] * R[d][c]
__device__ __forceinline__ void combine_body(const float* __restrict__ L,
                                             const float* __restrict__ R,
                                             float* __restrict__ O, int ldo,
                                             int nt, int r0) {
    __shared__ float L8[8][256];
    int t = threadIdx.x;
#pragma unroll
    for (int j = 0; j < 8; ++j) L8[j][t] = L[(r0 + j) * 256 + t];
    __syncthreads();
    float acc[8] = {};
    if (nt) {
        const float* rp = R + t * 256;
        for (int d = 0; d < 256; d += 4) {
            float4 rv = *(const float4*)(rp + d);
#pragma unroll
            for (int j = 0; j < 8; ++j) {
                float4 lv = *(const float4*)(&L8[j][d]);
                acc[j] += lv.x * rv.x + lv.y * rv.y + lv.z * rv.z + lv.w * rv.w;
            }
        }
    } else {
        for (int d = 0; d < 256; d += 4) {
            float r0v = R[(d + 0) * 256 + t];
            float r1v = R[(d + 1) * 256 + t];
            float r2v = R[(d + 2) * 256 + t];
            float r3v = R[(d + 3) * 256 + t];
#pragma unroll
            for (int j = 0; j < 8; ++j) {
                float4 lv = *(const float4*)(&L8[j][d]);
                acc[j] += lv.x * r0v + lv.y * r1v + lv.z * r2v + lv.w * r3v;
            }
        }
    }
#pragma unroll
    for (int j = 0; j < 8; ++j) O[(r0 + j) * ldo + t] = acc[j];
}

// 8 jobs x 32 row-blocks = 256 blocks
__global__ __launch_bounds__(256) void combine1(
    const float* __restrict__ Wq_t, const float* __restrict__ Wk_t,
    const float* __restrict__ Wv_t, const float* __restrict__ Wo_t,
    const float* __restrict__ Wq_c, const float* __restrict__ Wk_c,
    const float* __restrict__ Wv_c, const float* __restrict__ Wo_c,
    float* __restrict__ ws) {
    int job = blockIdx.x >> 5, rb = blockIdx.x & 31;
    const float *L, *R; float* O; int ldo, nt;
    if (job < 3)       { L = Wq_t + job * 65536; R = Wk_t + job * 65536; O = ws + OFF_ACAT + job * 256;    ldo = 768; nt = 1; }
    else if (job < 6)  { int s = job - 3; L = Wv_t + s * 65536; R = Wo_t + s * 65536; O = ws + OFF_VOCAT + s * 65536; ldo = 256; nt = 0; }
    else if (job == 6) { L = Wq_c; R = Wk_c; O = ws + OFF_AC;  ldo = 256; nt = 1; }
    else               { L = Wv_c; R = Wo_c; O = ws + OFF_VOC; ldo = 256; nt = 0; }
    combine_body(L, R, O, ldo, nt, rb * 8);
}

// bias precomputations (1 block)
__global__ __launch_bounds__(256) void bias1(
    const float* __restrict__ Wk_t, const float* __restrict__ Wo_t,
    const float* __restrict__ bq_t, const float* __restrict__ bv_t, const float* __restrict__ bo_t,
    const float* __restrict__ Wk_c, const float* __restrict__ Wo_c,
    const float* __restrict__ bq_c, const float* __restrict__ bv_c, const float* __restrict__ bo_c,
    float* __restrict__ ws) {
    int t = threadIdx.x;
    for (int s = 0; s < 3; ++s) {   // ab_cat[s*256+t] = sum_d bq_t[s][d]*Wk_t[s][t][d]
        const float* wk = Wk_t + (s * 256 + t) * 256;
        const float* bq = bq_t + s * 256;
        float a = 0;
        for (int d = 0; d < 256; ++d) a += bq[d] * wk[d];
        ws[OFF_ABCAT + s * 256 + t] = a;
    }
    float v = 0;                    // vb_sum[t] = sum_s (bv_t[s] @ Wo_t[s] + bo_t[s])[t]
    for (int s = 0; s < 3; ++s) {
        const float* wo = Wo_t + s * 65536;
        const float* bv = bv_t + s * 256;
        float a = 0;
        for (int d = 0; d < 256; ++d) a += bv[d] * wo[d * 256 + t];
        v += a + bo_t[s * 256 + t];
    }
    ws[OFF_VBSUM + t] = v;
    { float a = 0; const float* wk = Wk_c + t * 256;
      for (int d = 0; d < 256; ++d) a += bq_c[d] * wk[d];
      ws[OFF_ABC + t] = a; }
    { float a = 0;
      for (int d = 0; d < 256; ++d) a += bv_c[d] * Wo_c[d * 256 + t];
      ws[OFF_VBC + t] = a + bo_c[t]; }
}

// A2 = Vo_cat @ A_c  (96 blocks) ; ab2 (block 96)
__global__ __launch_bounds__(256) void combine2(float* __restrict__ ws) {
    int wg = blockIdx.x;
    if (wg < 96) {
        combine_body(ws + OFF_VOCAT, ws + OFF_AC, ws + OFF_A2, 256, 0, wg * 8);
    } else {
        int t = threadIdx.x;
        float a = 0;
        const float* vb = ws + OFF_VBSUM;
        const float* Ac = ws + OFF_AC;
        for (int e = 0; e < 256; ++e) a += vb[e] * Ac[e * 256 + t];
        ws[OFF_AB2 + t] = a + ws[OFF_ABC + t];
    }
}

// ---------------------------------------------------------------------------
// fp32 tiled GEMM: out[M][N] = (A (+Aadd)) @ B + bias ; tile 64x64, BK=16,
// 256 threads, 4x4 per thread. M,N multiples of 64; K multiple of 16.
__global__ __launch_bounds__(256) void gemm_bias(
    const float* __restrict__ A, const float* __restrict__ Aadd, int lda,
    const float* __restrict__ Bm, int ldb,
    const float* __restrict__ bias,
    float* __restrict__ out, int ldo, int Kd) {
    __shared__ float As[16][64];
    __shared__ float Bs[16][68];
    int tid = threadIdx.x;
    int bm = blockIdx.x * 64, bn = blockIdx.y * 64;
    int tx = tid & 15, ty = tid >> 4;
    float acc[4][4] = {};
    int ar = tid >> 2, ak = (tid & 3) * 4;
    int bk = tid >> 4, bq = (tid & 15) * 4;
    const float* Ab  = A + (size_t)(bm + ar) * lda + ak;
    const float* A2b = Aadd ? Aadd + (size_t)(bm + ar) * lda + ak : nullptr;
    const float* Bb  = Bm + (size_t)bk * ldb + bn + bq;
    for (int k0 = 0; k0 < Kd; k0 += 16) {
        float4 av = *(const float4*)(Ab + k0);
        if (Aadd) {
            float4 a2 = *(const float4*)(A2b + k0);
            av.x += a2.x; av.y += a2.y; av.z += a2.z; av.w += a2.w;
        }
        As[ak + 0][ar] = av.x; As[ak + 1][ar] = av.y;
        As[ak + 2][ar] = av.z; As[ak + 3][ar] = av.w;
        *(float4*)(&Bs[bk][bq]) = *(const float4*)(Bb + (size_t)k0 * ldb);
        __syncthreads();
#pragma unroll
        for (int kk = 0; kk < 16; ++kk) {
            float4 a4 = *(const float4*)(&As[kk][ty * 4]);
            float4 b4 = *(const float4*)(&Bs[kk][tx * 4]);
            float aa[4] = {a4.x, a4.y, a4.z, a4.w};
            float bb[4] = {b4.x, b4.y, b4.z, b4.w};
#pragma unroll
            for (int i = 0; i < 4; ++i)
#pragma unroll
                for (int j = 0; j < 4; ++j) acc[i][j] += aa[i] * bb[j];
        }
        __syncthreads();
    }
#pragma unroll
    for (int i = 0; i < 4; ++i) {
        int row = bm + ty * 4 + i;
        float b0 = bias[bn + tx * 4 + 0], b1 = bias[bn + tx * 4 + 1];
        float b2 = bias[bn + tx * 4 + 2], b3 = bias[bn + tx * 4 + 3];
        float4 o;
        o.x = acc[i][0] + b0; o.y = acc[i][1] + b1;
        o.z = acc[i][2] + b2; o.w = acc[i][3] + b3;
        *(float4*)(&out[(size_t)row * ldo + bn + tx * 4]) = o;
    }
}

// ---------------------------------------------------------------------------
// temporal attention core: one block per (s,bn). Reads knn_feat/knn_pe once.
// scores_k = SCALE * sum_c qk[c]*kv[k][c]; softmax over 16; wkv = sum attn*kv
__global__ __launch_bounds__(256) void attn_temporal(
    const float* __restrict__ knn_feat, const float* __restrict__ knn_pe,
    const float* __restrict__ qk_cat, float* __restrict__ wkv_cat) {
    int wg = blockIdx.x;              // s*4096 + bn
    int s = wg >> 12, bn = wg & 4095;
    int t = threadIdx.x;
    int lane = t & 63, wv = t >> 6;
    size_t base = (size_t)wg * 4096 + t;   // ((s*4096+bn)*16 + k)*256 + t
    float kv[16];
#pragma unroll
    for (int k = 0; k < 16; ++k)
        kv[k] = knn_feat[base + k * 256] + knn_pe[base + k * 256];
    float qv = qk_cat[(size_t)bn * 768 + s * 256 + t];
    __shared__ float red[4][16];
    __shared__ float sc[16];
#pragma unroll
    for (int k = 0; k < 16; ++k) {
        float v = qv * kv[k];
#pragma unroll
        for (int off = 32; off; off >>= 1) v += __shfl_xor(v, off, 64);
        if (lane == 0) red[wv][k] = v;
    }
    __syncthreads();
    if (t < 16) sc[t] = (red[0][t] + red[1][t] + red[2][t] + red[3][t]) * SCALE;
    __syncthreads();
    float mx = -1e30f;
#pragma unroll
    for (int k = 0; k < 16; ++k) mx = fmaxf(mx, sc[k]);
    float p[16], den = 0.f;
#pragma unroll
    for (int k = 0; k < 16; ++k) { p[k] = __expf(sc[k] - mx); den += p[k]; }
    float o = 0.f;
#pragma unroll
    for (int k = 0; k < 16; ++k) o += p[k] * kv[k];
    wkv_cat[(size_t)bn * 768 + s * 256 + t] = o * (1.f / den);
}

// cross-sensor attention core: one block per bn. Reads sampled_feat once.
__global__ __launch_bounds__(256) void attn_cross(
    const float* __restrict__ sampled, const int* __restrict__ mask,
    const float* __restrict__ qk2, float* __restrict__ ws2) {
    int bn = blockIdx.x;
    int t = threadIdx.x;
    int lane = t & 63, wv = t >> 6;
    size_t base = (size_t)bn * 8192 + t;   // (bn*32+m)*256 + t
    float smp[32];
#pragma unroll
    for (int m = 0; m < 32; ++m) smp[m] = sampled[base + m * 256];
    float qv = qk2[(size_t)bn * 256 + t];
    __shared__ float red[4][32];
    __shared__ float sc[32];
#pragma unroll
    for (int m = 0; m < 32; ++m) {
        float v = qv * smp[m];
#pragma unroll
        for (int off = 32; off; off >>= 1) v += __shfl_xor(v, off, 64);
        if (lane == 0) red[wv][m] = v;
    }
    __syncthreads();
    if (t < 32) {
        float v = (red[0][t] + red[1][t] + red[2][t] + red[3][t]) * SCALE;
        sc[t] = mask[(size_t)bn * 32 + t] ? v : -1e30f;
    }
    __syncthreads();
    float mx = -1e30f;
#pragma unroll
    for (int m = 0; m < 32; ++m) mx = fmaxf(mx, sc[m]);
    float den = 0.f, o = 0.f;
#pragma unroll
    for (int m = 0; m < 32; ++m) {
        float p = __expf(sc[m] - mx);
        den += p; o += p * smp[m];
    }
    ws2[(size_t)bn * 256 + t] = o / den;
}

// ---------------------------------------------------------------------------
extern "C" void kernel_launch(void* const* d_in, const int* in_sizes, int n_in,
                              void* d_out, int out_size, void* d_ws, size_t ws_size,
                              hipStream_t stream) {
    const float* feats    = (const float*)d_in[0];
    const float* pe       = (const float*)d_in[1];
    const float* knn_feat = (const float*)d_in[2];
    const float* knn_pe   = (const float*)d_in[3];
    const float* sampled  = (const float*)d_in[4];
    const float* Wq_t = (const float*)d_in[5];
    const float* Wk_t = (const float*)d_in[6];
    const float* Wv_t = (const float*)d_in[7];
    const float* Wo_t = (const float*)d_in[8];
    const float* bq_t = (const float*)d_in[9];
    // d_in[10] = bk_t : softmax-invariant, unused
    const float* bv_t = (const float*)d_in[11];
    const float* bo_t = (const float*)d_in[12];
    const float* Wq_c = (const float*)d_in[13];
    const float* Wk_c = (const float*)d_in[14];
    const float* Wv_c = (const float*)d_in[15];
    const float* Wo_c = (const float*)d_in[16];
    const float* bq_c = (const float*)d_in[17];
    // d_in[18] = bk_c : softmax-invariant, unused
    const float* bv_c = (const float*)d_in[19];
    const float* bo_c = (const float*)d_in[20];
    const int*   mask = (const int*)d_in[21];
    float* ws  = (float*)d_ws;
    float* out = (float*)d_out;

    hipLaunchKernelGGL(combine1, dim3(256), dim3(256), 0, stream,
                       Wq_t, Wk_t, Wv_t, Wo_t, Wq_c, Wk_c, Wv_c, Wo_c, ws);
    hipLaunchKernelGGL(bias1, dim3(1), dim3(256), 0, stream,
                       Wk_t, Wo_t, bq_t, bv_t, bo_t, Wk_c, Wo_c, bq_c, bv_c, bo_c, ws);
    hipLaunchKernelGGL(combine2, dim3(97), dim3(256), 0, stream, ws);
    // qk_cat = (feats+pe) @ A_cat + ab_cat           [4096,256]x[256,768]
    hipLaunchKernelGGL(gemm_bias, dim3(64, 12), dim3(256), 0, stream,
                       feats, pe, 256, ws + OFF_ACAT, 768, ws + OFF_ABCAT,
                       ws + OFF_QKCAT, 768, 256);
    // temporal attention (reads 402 MB of knn data once)
    hipLaunchKernelGGL(attn_temporal, dim3(12288), dim3(256), 0, stream,
                       knn_feat, knn_pe, ws + OFF_QKCAT, ws + OFF_WKV);
    // qk2 = wkv_cat @ A2 + ab2                       [4096,768]x[768,256]
    hipLaunchKernelGGL(gemm_bias, dim3(64, 4), dim3(256), 0, stream,
                       ws + OFF_WKV, nullptr, 768, ws + OFF_A2, 256, ws + OFF_AB2,
                       ws + OFF_QK2, 256, 768);
    // cross attention (reads 134 MB sampled once)
    hipLaunchKernelGGL(attn_cross, dim3(4096), dim3(256), 0, stream,
                       sampled, mask, ws + OFF_QK2, ws + OFF_WS2);
    // cs = ws2 @ Vo_c + vb_c -> d_out                [4096,256]x[256,256]
    hipLaunchKernelGGL(gemm_bias, dim3(64, 4), dim3(256), 0, stream,
                       ws + OFF_WS2, nullptr, 256, ws + OFF_VOC, 256, ws + OFF_VBC,
                       out, 256, 256);
}

// Round 4
// 702.659 us; speedup vs baseline: 1.0390x; 1.0390x over previous
//
#include <hip/hip_runtime.h>
#include <hip/hip_bf16.h>
#include <math.h>

// dims
#define SS 3
#define BB 2
#define NN 2048
#define KK 16
#define MM 32
#define CC 256
#define BN_TOT 4096
#define SCALE 0.0625f   // 1/sqrt(256)

// ws offsets (in floats)
#define OFF_ACAT   0          // A_cat   [256][768]  A_cat[c][s*256+c'] = sum_d Wq_t[s][c][d]*Wk_t[s][c'][d]
#define OFF_ABCAT  196608     // ab_cat  [768]
#define OFF_VOCAT  197376     // Vo_cat  [768][256]  Vo_cat[s*256+c][e] = sum_d Wv_t[s][c][d]*Wo_t[s][d][e]
#define OFF_VBSUM  393984     // vb_sum  [256]
#define OFF_AC     394240     // A_c     [256][256]
#define OFF_ABC    459776     // ab_c    [256]
#define OFF_VOC    460032     // Vo_c    [256][256]
#define OFF_VBC    525568     // vb_c    [256]
#define OFF_A2     525824     // A2      [768][256] = Vo_cat @ A_c
#define OFF_AB2    722432     // ab2     [256]
#define OFF_QKCAT  722688     // qk_cat  [4096][768]
#define OFF_WKV    3868416    // wkv_cat [4096][768]
#define OFF_QK2    7014144    // qk2     [4096][256]
#define OFF_WS2    8062720    // ws2     [4096][256]
// total 9111296 floats = ~36.4 MB

// ---------------------------------------------------------------------------
// small C-sized matmul helper: 8 output rows x 256 cols per block, 256 thr
// nt=1: OUT[r][c] = sum_d L[r][d] * R[c][d]
// nt=0: OUT[r][c] = sum_d L[r][d] * R[d][c]
__device__ __forceinline__ void combine_body(const float* __restrict__ L,
                                             const float* __restrict__ R,
                                             float* __restrict__ O, int ldo,
                                             int nt, int r0) {
    __shared__ float L8[8][256];
    int t = threadIdx.x;
#pragma unroll
    for (int j = 0; j < 8; ++j) L8[j][t] = L[(r0 + j) * 256 + t];
    __syncthreads();
    float acc[8] = {};
    if (nt) {
        const float* rp = R + t * 256;
        for (int d = 0; d < 256; d += 4) {
            float4 rv = *(const float4*)(rp + d);
#pragma unroll
            for (int j = 0; j < 8; ++j) {
                float4 lv = *(const float4*)(&L8[j][d]);
                acc[j] += lv.x * rv.x + lv.y * rv.y + lv.z * rv.z + lv.w * rv.w;
            }
        }
    } else {
        for (int d = 0; d < 256; d += 4) {
            float r0v = R[(d + 0) * 256 + t];
            float r1v = R[(d + 1) * 256 + t];
            float r2v = R[(d + 2) * 256 + t];
            float r3v = R[(d + 3) * 256 + t];
#pragma unroll
            for (int j = 0; j < 8; ++j) {
                float4 lv = *(const float4*)(&L8[j][d]);
                acc[j] += lv.x * r0v + lv.y * r1v + lv.z * r2v + lv.w * r3v;
            }
        }
    }
#pragma unroll
    for (int j = 0; j < 8; ++j) O[(r0 + j) * ldo + t] = acc[j];
}

// 8 jobs x 32 row-blocks = 256 blocks, + 5 bias blocks (256..260)
__global__ __launch_bounds__(256) void combine1(
    const float* __restrict__ Wq_t, const float* __restrict__ Wk_t,
    const float* __restrict__ Wv_t, const float* __restrict__ Wo_t,
    const float* __restrict__ Wq_c, const float* __restrict__ Wk_c,
    const float* __restrict__ Wv_c, const float* __restrict__ Wo_c,
    const float* __restrict__ bq_t, const float* __restrict__ bv_t,
    const float* __restrict__ bo_t,
    const float* __restrict__ bq_c, const float* __restrict__ bv_c,
    const float* __restrict__ bo_c,
    float* __restrict__ ws) {
    int t = threadIdx.x;
    if (blockIdx.x >= 256) {     // bias jobs
        int jb = blockIdx.x - 256;
        if (jb < 3) {            // ab_cat[s*256+t] = sum_d bq_t[s][d]*Wk_t[s][t][d]
            const float* wk = Wk_t + (jb * 256 + t) * 256;
            const float* bq = bq_t + jb * 256;
            float a = 0;
            for (int d = 0; d < 256; ++d) a += bq[d] * wk[d];
            ws[OFF_ABCAT + jb * 256 + t] = a;
        } else if (jb == 3) {    // vb_sum[t] = sum_s (bv_t[s] @ Wo_t[s] + bo_t[s])[t]
            float v = 0;
            for (int s = 0; s < 3; ++s) {
                const float* wo = Wo_t + s * 65536;
                const float* bv = bv_t + s * 256;
                float a = 0;
                for (int d = 0; d < 256; ++d) a += bv[d] * wo[d * 256 + t];
                v += a + bo_t[s * 256 + t];
            }
            ws[OFF_VBSUM + t] = v;
        } else {                 // ab_c, vb_c
            float a = 0; const float* wk = Wk_c + t * 256;
            for (int d = 0; d < 256; ++d) a += bq_c[d] * wk[d];
            ws[OFF_ABC + t] = a;
            float b = 0;
            for (int d = 0; d < 256; ++d) b += bv_c[d] * Wo_c[d * 256 + t];
            ws[OFF_VBC + t] = b + bo_c[t];
        }
        return;
    }
    int job = blockIdx.x >> 5, rb = blockIdx.x & 31;
    const float *L, *R; float* O; int ldo, nt;
    if (job < 3)       { L = Wq_t + job * 65536; R = Wk_t + job * 65536; O = ws + OFF_ACAT + job * 256;    ldo = 768; nt = 1; }
    else if (job < 6)  { int s = job - 3; L = Wv_t + s * 65536; R = Wo_t + s * 65536; O = ws + OFF_VOCAT + s * 65536; ldo = 256; nt = 0; }
    else if (job == 6) { L = Wq_c; R = Wk_c; O = ws + OFF_AC;  ldo = 256; nt = 1; }
    else               { L = Wv_c; R = Wo_c; O = ws + OFF_VOC; ldo = 256; nt = 0; }
    combine_body(L, R, O, ldo, nt, rb * 8);
}

// A2 = Vo_cat @ A_c  (96 blocks) ; ab2 (block 96)
__global__ __launch_bounds__(256) void combine2(float* __restrict__ ws) {
    int wg = blockIdx.x;
    if (wg < 96) {
        combine_body(ws + OFF_VOCAT, ws + OFF_AC, ws + OFF_A2, 256, 0, wg * 8);
    } else {
        int t = threadIdx.x;
        float a = 0;
        const float* vb = ws + OFF_VBSUM;
        const float* Ac = ws + OFF_AC;
        for (int e = 0; e < 256; ++e) a += vb[e] * Ac[e * 256 + t];
        ws[OFF_AB2 + t] = a + ws[OFF_ABC + t];
    }
}

// ---------------------------------------------------------------------------
// fp32 GEMM: out[M][N] = (A (+Aadd)) @ B + bias ; tile 64x64, BK=16, 256 thr,
// 4x4/thread. A staged in LDS (padded, conflict-free); B streamed from
// global (tiny, L2-resident) -> inner loop is 1 ds_read_b128 + 1 global f4
// per 16 FMA instead of 3 LDS reads (was LDS-pipe bound).
__global__ __launch_bounds__(256) void gemm_bias(
    const float* __restrict__ A, const float* __restrict__ Aadd, int lda,
    const float* __restrict__ Bm, int ldb,
    const float* __restrict__ bias,
    float* __restrict__ out, int ldo, int Kd) {
    __shared__ float As[16][68];       // As[k][row], pad 68 -> 2-way max
    int tid = threadIdx.x;
    int bm = blockIdx.x * 64, bn = blockIdx.y * 64;
    int tx = tid & 15, ty = tid >> 4;
    float acc[4][4] = {};
    int ar = tid >> 2, ak = (tid & 3) * 4;
    const float* Ab  = A + (size_t)(bm + ar) * lda + ak;
    const float* A2b = Aadd ? Aadd + (size_t)(bm + ar) * lda + ak : nullptr;
    const float* Bb  = Bm + bn + tx * 4;
    for (int k0 = 0; k0 < Kd; k0 += 16) {
        float4 av = *(const float4*)(Ab + k0);
        if (Aadd) {
            float4 a2 = *(const float4*)(A2b + k0);
            av.x += a2.x; av.y += a2.y; av.z += a2.z; av.w += a2.w;
        }
        As[ak + 0][ar] = av.x; As[ak + 1][ar] = av.y;
        As[ak + 2][ar] = av.z; As[ak + 3][ar] = av.w;
        __syncthreads();
#pragma unroll
        for (int kk = 0; kk < 16; ++kk) {
            float4 b4 = *(const float4*)(Bb + (size_t)(k0 + kk) * ldb);
            float4 a4 = *(const float4*)(&As[kk][ty * 4]);
            float aa[4] = {a4.x, a4.y, a4.z, a4.w};
            float bb[4] = {b4.x, b4.y, b4.z, b4.w};
#pragma unroll
            for (int i = 0; i < 4; ++i)
#pragma unroll
                for (int j = 0; j < 4; ++j) acc[i][j] += aa[i] * bb[j];
        }
        __syncthreads();
    }
#pragma unroll
    for (int i = 0; i < 4; ++i) {
        int row = bm + ty * 4 + i;
        float b0 = bias[bn + tx * 4 + 0], b1 = bias[bn + tx * 4 + 1];
        float b2 = bias[bn + tx * 4 + 2], b3 = bias[bn + tx * 4 + 3];
        float4 o;
        o.x = acc[i][0] + b0; o.y = acc[i][1] + b1;
        o.z = acc[i][2] + b2; o.w = acc[i][3] + b3;
        *(float4*)(&out[(size_t)row * ldo + bn + tx * 4]) = o;
    }
}

// ---------------------------------------------------------------------------
// temporal attention: ONE WAVE per (s,bn). float4 loads, folding butterfly
// (17 shuffles), uniform-lane broadcast (v_readlane, no DS), no LDS/syncs.
__global__ __launch_bounds__(256) void attn_temporal(
    const float* __restrict__ knn_feat, const float* __restrict__ knn_pe,
    const float* __restrict__ qk_cat, float* __restrict__ wkv_cat) {
    int unit = blockIdx.x * 4 + (threadIdx.x >> 6);   // s*4096 + bn
    int lane = threadIdx.x & 63;
    int s = unit >> 12, bn = unit & 4095;
    size_t base = (size_t)unit * 4096 + lane * 4;
    float4 kv[16];
#pragma unroll
    for (int k = 0; k < 16; ++k) {
        float4 f = *(const float4*)(knn_feat + base + k * 256);
        float4 p = *(const float4*)(knn_pe   + base + k * 256);
        kv[k] = make_float4(f.x + p.x, f.y + p.y, f.z + p.z, f.w + p.w);
    }
    float4 q = *(const float4*)(qk_cat + (size_t)bn * 768 + s * 256 + lane * 4);
    float v[16];
#pragma unroll
    for (int k = 0; k < 16; ++k)
        v[k] = q.x * kv[k].x + q.y * kv[k].y + q.z * kv[k].z + q.w * kv[k].w;
    // fold 16 values across 64 lanes: after masks 32/16/8/4 each lane holds
    // the (16-lane-partial) sum for k=(lane>>2)&15; masks 1/2 finish it.
    { int hi = lane & 32;
#pragma unroll
      for (int j = 0; j < 8; ++j) {
          float send = hi ? v[j] : v[j + 8];
          float keep = hi ? v[j + 8] : v[j];
          v[j] = keep + __shfl_xor(send, 32, 64);
      } }
    { int hi = lane & 16;
#pragma unroll
      for (int j = 0; j < 4; ++j) {
          float send = hi ? v[j] : v[j + 4];
          float keep = hi ? v[j + 4] : v[j];
          v[j] = keep + __shfl_xor(send, 16, 64);
      } }
    { int hi = lane & 8;
#pragma unroll
      for (int j = 0; j < 2; ++j) {
          float send = hi ? v[j] : v[j + 2];
          float keep = hi ? v[j + 2] : v[j];
          v[j] = keep + __shfl_xor(send, 8, 64);
      } }
    { int hi = lane & 4;
      float send = hi ? v[0] : v[1];
      float keep = hi ? v[1] : v[0];
      v[0] = keep + __shfl_xor(send, 4, 64); }
    float r = v[0];
    r += __shfl_xor(r, 1, 64);
    r += __shfl_xor(r, 2, 64);
    // broadcast all 16 scores to every lane (uniform src lane -> readlane)
    float sc[16];
#pragma unroll
    for (int k = 0; k < 16; ++k) sc[k] = __shfl(r, k << 2, 64) * SCALE;
    float mx = sc[0];
#pragma unroll
    for (int k = 1; k < 16; ++k) mx = fmaxf(mx, sc[k]);
    float den = 0.f;
#pragma unroll
    for (int k = 0; k < 16; ++k) { sc[k] = __expf(sc[k] - mx); den += sc[k]; }
    float inv = 1.f / den;
    float ox = 0, oy = 0, oz = 0, ow = 0;
#pragma unroll
    for (int k = 0; k < 16; ++k) {
        ox += sc[k] * kv[k].x; oy += sc[k] * kv[k].y;
        oz += sc[k] * kv[k].z; ow += sc[k] * kv[k].w;
    }
    float4 o = make_float4(ox * inv, oy * inv, oz * inv, ow * inv);
    *(float4*)(wkv_cat + (size_t)bn * 768 + s * 256 + lane * 4) = o;
}

// cross-sensor attention: block per bn, wave w owns m in [w*8, w*8+8).
// float4 loads; fold (10 shuffles); per-wave partial outputs combined in LDS.
// sampled is read exactly once.
__global__ __launch_bounds__(256) void attn_cross(
    const float* __restrict__ sampled, const int* __restrict__ mask,
    const float* __restrict__ qk2, float* __restrict__ ws2) {
    int bn = blockIdx.x;
    int t = threadIdx.x;
    int w = t >> 6, lane = t & 63;
    __shared__ float sc_lds[32];
    __shared__ float obuf[4][256];
    size_t base = (size_t)bn * 8192 + (size_t)(w * 8) * 256 + lane * 4;
    float4 sm[8];
#pragma unroll
    for (int j = 0; j < 8; ++j) sm[j] = *(const float4*)(sampled + base + j * 256);
    float4 q = *(const float4*)(qk2 + (size_t)bn * 256 + lane * 4);
    float v[8];
#pragma unroll
    for (int j = 0; j < 8; ++j)
        v[j] = q.x * sm[j].x + q.y * sm[j].y + q.z * sm[j].z + q.w * sm[j].w;
    { int hi = lane & 32;
#pragma unroll
      for (int j = 0; j < 4; ++j) {
          float send = hi ? v[j] : v[j + 4];
          float keep = hi ? v[j + 4] : v[j];
          v[j] = keep + __shfl_xor(send, 32, 64);
      } }
    { int hi = lane & 16;
#pragma unroll
      for (int j = 0; j < 2; ++j) {
          float send = hi ? v[j] : v[j + 2];
          float keep = hi ? v[j + 2] : v[j];
          v[j] = keep + __shfl_xor(send, 16, 64);
      } }
    { int hi = lane & 8;
      float send = hi ? v[0] : v[1];
      float keep = hi ? v[1] : v[0];
      v[0] = keep + __shfl_xor(send, 8, 64); }
    float r = v[0];
    r += __shfl_xor(r, 1, 64);
    r += __shfl_xor(r, 2, 64);
    r += __shfl_xor(r, 4, 64);
    // lane m_local*8 holds score for m = w*8 + m_local
    if ((lane & 7) == 0) {
        int m = w * 8 + (lane >> 3);
        int valid = mask[(size_t)bn * 32 + m];
        sc_lds[m] = valid ? r * SCALE : -1e30f;
    }
    __syncthreads();
    float scv[32];
#pragma unroll
    for (int i = 0; i < 8; ++i) {
        float4 v4 = *(const float4*)(&sc_lds[i * 4]);
        scv[i * 4 + 0] = v4.x; scv[i * 4 + 1] = v4.y;
        scv[i * 4 + 2] = v4.z; scv[i * 4 + 3] = v4.w;
    }
    float mx = scv[0];
#pragma unroll
    for (int m = 1; m < 32; ++m) mx = fmaxf(mx, scv[m]);
    float den = 0.f;
    float el[8] = {};
#pragma unroll
    for (int m = 0; m < 32; ++m) {
        float ex = __expf(scv[m] - mx);
        den += ex;
        el[m & 7] = ((m >> 3) == w) ? ex : el[m & 7];   // static index, cndmask
    }
    float inv = 1.f / den;
    float ox = 0, oy = 0, oz = 0, ow = 0;
#pragma unroll
    for (int j = 0; j < 8; ++j) {
        ox += el[j] * sm[j].x; oy += el[j] * sm[j].y;
        oz += el[j] * sm[j].z; ow += el[j] * sm[j].w;
    }
    *(float4*)(&obuf[w][lane * 4]) =
        make_float4(ox * inv, oy * inv, oz * inv, ow * inv);
    __syncthreads();
    float o = obuf[0][t] + obuf[1][t] + obuf[2][t] + obuf[3][t];
    ws2[(size_t)bn * 256 + t] = o;
}

// ---------------------------------------------------------------------------
extern "C" void kernel_launch(void* const* d_in, const int* in_sizes, int n_in,
                              void* d_out, int out_size, void* d_ws, size_t ws_size,
                              hipStream_t stream) {
    const float* feats    = (const float*)d_in[0];
    const float* pe       = (const float*)d_in[1];
    const float* knn_feat = (const float*)d_in[2];
    const float* knn_pe   = (const float*)d_in[3];
    const float* sampled  = (const float*)d_in[4];
    const float* Wq_t = (const float*)d_in[5];
    const float* Wk_t = (const float*)d_in[6];
    const float* Wv_t = (const float*)d_in[7];
    const float* Wo_t = (const float*)d_in[8];
    const float* bq_t = (const float*)d_in[9];
    // d_in[10] = bk_t : softmax-invariant, unused
    const float* bv_t = (const float*)d_in[11];
    const float* bo_t = (const float*)d_in[12];
    const float* Wq_c = (const float*)d_in[13];
    const float* Wk_c = (const float*)d_in[14];
    const float* Wv_c = (const float*)d_in[15];
    const float* Wo_c = (const float*)d_in[16];
    const float* bq_c = (const float*)d_in[17];
    // d_in[18] = bk_c : softmax-invariant, unused
    const float* bv_c = (const float*)d_in[19];
    const float* bo_c = (const float*)d_in[20];
    const int*   mask = (const int*)d_in[21];
    float* ws  = (float*)d_ws;
    float* out = (float*)d_out;

    hipLaunchKernelGGL(combine1, dim3(261), dim3(256), 0, stream,
                       Wq_t, Wk_t, Wv_t, Wo_t, Wq_c, Wk_c, Wv_c, Wo_c,
                       bq_t, bv_t, bo_t, bq_c, bv_c, bo_c, ws);
    hipLaunchKernelGGL(combine2, dim3(97), dim3(256), 0, stream, ws);
    // qk_cat = (feats+pe) @ A_cat + ab_cat           [4096,256]x[256,768]
    hipLaunchKernelGGL(gemm_bias, dim3(64, 12), dim3(256), 0, stream,
                       feats, pe, 256, ws + OFF_ACAT, 768, ws + OFF_ABCAT,
                       ws + OFF_QKCAT, 768, 256);
    // temporal attention (reads 402 MB of knn data once)
    hipLaunchKernelGGL(attn_temporal, dim3(3072), dim3(256), 0, stream,
                       knn_feat, knn_pe, ws + OFF_QKCAT, ws + OFF_WKV);
    // qk2 = wkv_cat @ A2 + ab2                       [4096,768]x[768,256]
    hipLaunchKernelGGL(gemm_bias, dim3(64, 4), dim3(256), 0, stream,
                       ws + OFF_WKV, nullptr, 768, ws + OFF_A2, 256, ws + OFF_AB2,
                       ws + OFF_QK2, 256, 768);
    // cross attention (reads 134 MB sampled once)
    hipLaunchKernelGGL(attn_cross, dim3(4096), dim3(256), 0, stream,
                       sampled, mask, ws + OFF_QK2, ws + OFF_WS2);
    // cs = ws2 @ Vo_c + vb_c -> d_out                [4096,256]x[256,256]
    hipLaunchKernelGGL(gemm_bias, dim3(64, 4), dim3(256), 0, stream,
                       ws + OFF_WS2, nullptr, 256, ws + OFF_VOC, 256, ws + OFF_VBC,
                       out, 256, 256);
}